// Round 1
// baseline (496.644 us; speedup 1.0000x reference)
//
#include <hip/hip_runtime.h>

#define K_DIM 7168
#define N_DIM 4096
#define KBLKS 56   // K/128
#define FP8MAX 448.0f

typedef float f32x4 __attribute__((ext_vector_type(4)));

#define GLOBAL_AS __attribute__((address_space(1)))
#define LDS_AS __attribute__((address_space(3)))

__device__ __forceinline__ void gload_lds16(const void* g, void* l) {
  __builtin_amdgcn_global_load_lds((GLOBAL_AS void*)g, (LDS_AS void*)l, 16, 0, 0);
}

__device__ __forceinline__ int pack_fp8x4(float a, float b, float c, float d) {
  int v = __builtin_amdgcn_cvt_pk_fp8_f32(a, b, 0, false);
  v = __builtin_amdgcn_cvt_pk_fp8_f32(c, d, v, true);
  return v;
}

// ---- activation quant: per-(row, 128-block) amax -> scale -> fp8 ----
// scale written transposed: asT[kb*M + m] for coalesced GEMM staging.
__global__ void quant_x_kernel(const float* __restrict__ x,
                               unsigned char* __restrict__ xq,
                               float* __restrict__ asT, int M) {
  int gid = (int)((blockIdx.x * blockDim.x + threadIdx.x) >> 5);
  int lane = threadIdx.x & 31;
  if (gid >= M * KBLKS) return;
  int m = gid / KBLKS;
  int kb = gid - m * KBLKS;
  size_t off = (size_t)m * K_DIM + kb * 128 + lane * 4;
  float4 v = *(const float4*)(x + off);
  float amax = fmaxf(fmaxf(fabsf(v.x), fabsf(v.y)), fmaxf(fabsf(v.z), fabsf(v.w)));
#pragma unroll
  for (int d = 16; d; d >>= 1) amax = fmaxf(amax, __shfl_xor(amax, d));
  // exact replication of reference: scale = max(amax,1e-12)/448 (f32 RNE div),
  // q = fp8_rne(x / scale) (true f32 division, not reciprocal-mul)
  float scale = fmaxf(amax, 1e-12f) / FP8MAX;
  int pk = pack_fp8x4(v.x / scale, v.y / scale, v.z / scale, v.w / scale);
  *(int*)(xq + off) = pk;
  if (lane == 0) asT[(size_t)kb * M + m] = scale;
}

// ---- weight fp8 cast (input values are already exactly fp8-representable) ----
__global__ void quant_w_kernel(const float* __restrict__ w,
                               unsigned char* __restrict__ wq, long n4) {
  long i = (long)blockIdx.x * blockDim.x + threadIdx.x;
  if (i >= n4) return;
  float4 v = *(const float4*)(w + i * 4);
  ((int*)wq)[i] = pack_fp8x4(v.x, v.y, v.z, v.w);
}

// ---- blockwise-scaled fp8 GEMM: C[m,n] = sum_kb (sum_{k in kb} xq*wq) * as[m,kb]*ws[nb,kb]
// 128x128 tile, BK=128, 4 waves (2x2 of 64x64), 16x16x32 fp8 MFMA.
// LDS tiles XOR-swizzled (byte ^= (row&7)<<4) via pre-swizzled global source
// (global_load_lds writes linearly), matching swizzle on ds_read_b64.
__global__ __launch_bounds__(256, 2)
void gemm_fp8_blk(const unsigned char* __restrict__ xq,
                  const unsigned char* __restrict__ wq,
                  const float* __restrict__ asT,
                  const float* __restrict__ wscale,
                  float* __restrict__ out, int M) {
  __shared__ unsigned char ldsA[128 * 128];
  __shared__ unsigned char ldsB[128 * 128];
  __shared__ float ldsAS[128];

  const int bid = blockIdx.x;
  const int per = gridDim.x >> 3;                  // grid % 8 == 0 (1024)
  const int swz = (bid & 7) * per + (bid >> 3);    // XCD-aware swizzle
  const int bn = swz & ((N_DIM / 128) - 1);
  const int bm = swz / (N_DIM / 128);
  const int m0 = bm * 128, n0 = bn * 128;

  const int tid = threadIdx.x;
  const int wv = tid >> 6, lane = tid & 63;
  const int wm = (wv >> 1) * 64, wn = (wv & 1) * 64;

  f32x4 acc[4][4] = {};

  auto stage = [&](int kb) {
    // A tile: 16KB, 4 gload_lds per thread-slot; wave-uniform LDS base + lane*16.
#pragma unroll
    for (int i = 0; i < 4; ++i) {
      int o = i * 4096 + wv * 1024 + lane * 16;
      int row = o >> 7;
      int col = (o & 127) ^ ((row & 7) << 4);   // inverse-swizzle on SOURCE
      gload_lds16(xq + (size_t)(m0 + row) * K_DIM + (size_t)kb * 128 + col,
                  ldsA + i * 4096 + wv * 1024);
    }
#pragma unroll
    for (int i = 0; i < 4; ++i) {
      int o = i * 4096 + wv * 1024 + lane * 16;
      int row = o >> 7;
      int col = (o & 127) ^ ((row & 7) << 4);
      gload_lds16(wq + (size_t)(n0 + row) * K_DIM + (size_t)kb * 128 + col,
                  ldsB + i * 4096 + wv * 1024);
    }
    if (tid < 128) ldsAS[tid] = asT[(size_t)kb * M + m0 + tid];
  };

  stage(0);

  const int wsrow = bn * KBLKS;
  const int rsel = lane & 15;
  const int ksel = (lane >> 4) << 3;   // k-group byte offset within 32B
  const int jrow = (lane >> 4) << 2;   // C/D row group: row = jrow + reg

  for (int kb = 0; kb < KBLKS; ++kb) {
    __syncthreads();   // stage(kb) drained (vmcnt(0) at barrier)

    f32x4 as4[4];
#pragma unroll
    for (int mi = 0; mi < 4; ++mi)
      as4[mi] = *(const f32x4*)&ldsAS[wm + mi * 16 + jrow];

    long af[4][4], bf[4][4];
#pragma unroll
    for (int kk = 0; kk < 4; ++kk) {
#pragma unroll
      for (int i = 0; i < 4; ++i) {
        int rowa = wm + i * 16 + rsel;
        int cola = (kk * 32 + ksel) ^ ((rowa & 7) << 4);   // swizzle on READ
        af[kk][i] = *(const long*)(ldsA + rowa * 128 + cola);
        int rowb = wn + i * 16 + rsel;
        int colb = (kk * 32 + ksel) ^ ((rowb & 7) << 4);
        bf[kk][i] = *(const long*)(ldsB + rowb * 128 + colb);
      }
    }
    __syncthreads();   // all LDS reads done; tiles reusable

    if (kb + 1 < KBLKS) stage(kb + 1);  // prefetch in flight during MFMAs

    float wsc = wscale[wsrow + kb];     // block-uniform -> s_load
#pragma unroll
    for (int mi = 0; mi < 4; ++mi) {
      f32x4 comb = as4[mi] * wsc;
#pragma unroll
      for (int ni = 0; ni < 4; ++ni) {
        f32x4 t = {0.f, 0.f, 0.f, 0.f};
#pragma unroll
        for (int kk = 0; kk < 4; ++kk)
          t = __builtin_amdgcn_mfma_f32_16x16x32_fp8_fp8(af[kk][mi], bf[kk][ni], t, 0, 0, 0);
        acc[mi][ni] += t * comb;        // per-reg row matches as4 j-index
      }
    }
  }

  // epilogue: C/D layout col=lane&15, row=(lane>>4)*4+reg (dtype-independent)
#pragma unroll
  for (int mi = 0; mi < 4; ++mi) {
#pragma unroll
    for (int j = 0; j < 4; ++j) {
      int rowm = m0 + wm + mi * 16 + jrow + j;
      float* op = out + (size_t)rowm * N_DIM + n0 + wn + rsel;
#pragma unroll
      for (int ni = 0; ni < 4; ++ni) op[ni * 16] = acc[mi][ni][j];
    }
  }
}

extern "C" void kernel_launch(void* const* d_in, const int* in_sizes, int n_in,
                              void* d_out, int out_size, void* d_ws, size_t ws_size,
                              hipStream_t stream) {
  const float* x    = (const float*)d_in[0];
  const float* wgt  = (const float*)d_in[1];
  const float* wsc  = (const float*)d_in[2];
  float* out = (float*)d_out;

  const int K = K_DIM, N = N_DIM;
  const int M = in_sizes[0] / K;                 // 4096

  unsigned char* xq = (unsigned char*)d_ws;      // M*K fp8
  unsigned char* wq = xq + (size_t)M * K;        // N*K fp8
  float* asT = (float*)(wq + (size_t)N * K);     // [KBLKS][M] f32

  int groups = M * (K / 128);
  quant_x_kernel<<<(groups * 32 + 255) / 256, 256, 0, stream>>>(x, xq, asT, M);
  quant_w_kernel<<<((long)N * K / 4 + 255) / 256, 256, 0, stream>>>(wgt, wq, (long)N * K / 4);

  dim3 grid((M / 128) * (N / 128));              // 1024
  gemm_fp8_blk<<<grid, 256, 0, stream>>>(xq, wq, asT, wsc, out, M);
}